// Round 1
// baseline (3285.816 us; speedup 1.0000x reference)
//
#include <hip/hip_runtime.h>
#include <hip/hip_bf16.h>

#define N_NODES 100000
#define N_EDGES 1600000
#define IN_C 128
#define HID_C 256
#define OUT_C 128

// ---------------- SpMM: out[row[e]] += val[e] * H[col[e]]  (atomic) ----------------
__global__ void spmm_atomic(const float* __restrict__ H, const int* __restrict__ rows,
                            const int* __restrict__ cols, const float* __restrict__ vals,
                            float* __restrict__ out, int E, int C)
{
    int gid = blockIdx.x * blockDim.x + threadIdx.x;
    int wave = gid >> 6;
    int lane = gid & 63;
    int nwaves = (gridDim.x * blockDim.x) >> 6;
    for (int e = wave; e < E; e += nwaves) {
        int r = rows[e];
        int c = cols[e];
        float v = vals[e];
        const float* src = H + (size_t)c * C;
        float* dst = out + (size_t)r * C;
        for (int ch = lane; ch < C; ch += 64) {
            atomicAdd(&dst[ch], v * src[ch]);
        }
    }
}

// ---------------- GEMM: Y[n,m] = relu?(sum_k A[n,k] * W[m,k] + bias[m]) ----------------
// A: [N,K] row-major, W: [M,K] row-major (torch Linear layout), Y: [N,M]
#define BN 64
#define BM 64
#define BK 16

__global__ __launch_bounds__(256) void gemm_bias_act(
    const float* __restrict__ A, const float* __restrict__ W,
    const float* __restrict__ bias, float* __restrict__ Y,
    int N, int K, int M, int relu)
{
    __shared__ float As[BK][BN + 1];
    __shared__ float Ws[BK][BM + 1];

    int bn = blockIdx.x * BN;
    int bm = blockIdx.y * BM;
    int tid = threadIdx.x;
    int tn = tid & 15;   // 0..15 -> n sub-tile (each covers 4)
    int tm = tid >> 4;   // 0..15 -> m sub-tile (each covers 4)

    float acc[4][4] = {{0.f}};

    int lr = tid >> 2;         // 0..63 row within tile
    int lk = (tid & 3) * 4;    // 0,4,8,12 k within tile

    for (int k0 = 0; k0 < K; k0 += BK) {
        // load A tile (guard N), W tile (M is multiple of 64, no guard)
        int n = bn + lr;
        float4 a;
        if (n < N) a = *(const float4*)&A[(size_t)n * K + k0 + lk];
        else       a = float4{0.f, 0.f, 0.f, 0.f};
        As[lk + 0][lr] = a.x; As[lk + 1][lr] = a.y;
        As[lk + 2][lr] = a.z; As[lk + 3][lr] = a.w;

        int m = bm + lr;
        float4 w = *(const float4*)&W[(size_t)m * K + k0 + lk];
        Ws[lk + 0][lr] = w.x; Ws[lk + 1][lr] = w.y;
        Ws[lk + 2][lr] = w.z; Ws[lk + 3][lr] = w.w;

        __syncthreads();

        #pragma unroll
        for (int kk = 0; kk < BK; ++kk) {
            float ar[4], br[4];
            #pragma unroll
            for (int i = 0; i < 4; ++i) ar[i] = As[kk][tn * 4 + i];
            #pragma unroll
            for (int j = 0; j < 4; ++j) br[j] = Ws[kk][tm * 4 + j];
            #pragma unroll
            for (int i = 0; i < 4; ++i)
                #pragma unroll
                for (int j = 0; j < 4; ++j)
                    acc[i][j] += ar[i] * br[j];
        }
        __syncthreads();
    }

    #pragma unroll
    for (int i = 0; i < 4; ++i) {
        int n = bn + tn * 4 + i;
        if (n >= N) continue;
        #pragma unroll
        for (int j = 0; j < 4; ++j) {
            int m = bm + tm * 4 + j;
            float v = acc[i][j] + (bias ? bias[m] : 0.f);
            if (relu) v = fmaxf(v, 0.f);
            Y[(size_t)n * M + m] = v;
        }
    }
}

// ---------------- L2 normalize rows (C=128), adding bias first ----------------
__global__ void l2norm_bias(float* __restrict__ Y, const float* __restrict__ bias, int N)
{
    const int C = OUT_C;
    int wid = threadIdx.x >> 6;
    int lane = threadIdx.x & 63;
    int row = blockIdx.x * (blockDim.x >> 6) + wid;
    if (row >= N) return;
    float* p = Y + (size_t)row * C;
    float2 v = *(float2*)&p[lane * 2];
    v.x += bias[lane * 2 + 0];
    v.y += bias[lane * 2 + 1];
    float ss = v.x * v.x + v.y * v.y;
    #pragma unroll
    for (int off = 1; off < 64; off <<= 1)
        ss += __shfl_xor(ss, off);
    float norm = sqrtf(ss);
    float scale = 1.0f / fmaxf(norm, 1e-12f);
    v.x *= scale;
    v.y *= scale;
    *(float2*)&p[lane * 2] = v;
}

extern "C" void kernel_launch(void* const* d_in, const int* in_sizes, int n_in,
                              void* d_out, int out_size, void* d_ws, size_t ws_size,
                              hipStream_t stream) {
    const float* x        = (const float*)d_in[0];
    const int*   edge_row = (const int*)d_in[1];
    const int*   edge_col = (const int*)d_in[2];
    const float* edge_val = (const float*)d_in[3];
    const float* W1       = (const float*)d_in[4];
    const float* b1       = (const float*)d_in[5];
    const float* W2       = (const float*)d_in[6];
    const float* b2       = (const float*)d_in[7];
    const float* W3       = (const float*)d_in[8];
    const float* b3       = (const float*)d_in[9];
    float* out = (float*)d_out;

    const int N = N_NODES, E = N_EDGES;

    // workspace layout (floats):
    //   A: [N, 128]  (spmm(x) result; later reused for h2@W3.T)
    //   B: [N, 256]  (h1; later reused for h2)
    //   C: [N, 256]  (spmm(h1) result)
    float* A = (float*)d_ws;
    float* B = A + (size_t)N * IN_C;
    float* C = B + (size_t)N * HID_C;

    // zero the atomic accumulators
    hipMemsetAsync(A, 0, (size_t)N * IN_C * sizeof(float), stream);
    hipMemsetAsync(C, 0, (size_t)N * HID_C * sizeof(float), stream);
    hipMemsetAsync(out, 0, (size_t)N * OUT_C * sizeof(float), stream);

    const int spmm_blocks = (E + 3) / 4;  // one wave per edge (4 waves/block)

    // Layer 1: A = spmm(x) [C=128]; B = relu(A @ W1.T + b1) [N,256]
    spmm_atomic<<<spmm_blocks, 256, 0, stream>>>(x, edge_row, edge_col, edge_val, A, E, IN_C);
    {
        dim3 grid((N + BN - 1) / BN, HID_C / BM);
        gemm_bias_act<<<grid, 256, 0, stream>>>(A, W1, b1, B, N, IN_C, HID_C, 1);
    }

    // Layer 2: C = spmm(B) [C=256]; B = relu(C @ W2.T + b2) [N,256]
    spmm_atomic<<<spmm_blocks, 256, 0, stream>>>(B, edge_row, edge_col, edge_val, C, E, HID_C);
    {
        dim3 grid((N + BN - 1) / BN, HID_C / BM);
        gemm_bias_act<<<grid, 256, 0, stream>>>(C, W2, b2, B, N, HID_C, HID_C, 1);
    }

    // Layer 3 (reordered): A = B @ W3.T [N,128]; out = spmm(A) [C=128]; out = normalize(out + b3)
    {
        dim3 grid((N + BN - 1) / BN, OUT_C / BM);
        gemm_bias_act<<<grid, 256, 0, stream>>>(B, W3, nullptr, A, N, HID_C, OUT_C, 0);
    }
    spmm_atomic<<<spmm_blocks, 256, 0, stream>>>(A, edge_row, edge_col, edge_val, out, E, OUT_C);
    l2norm_bias<<<(N + 3) / 4, 256, 0, stream>>>(out, b3, N);
}

// Round 2
// 1303.735 us; speedup vs baseline: 2.5203x; 2.5203x over previous
//
#include <hip/hip_runtime.h>
#include <hip/hip_bf16.h>

#define N_NODES 100000
#define N_EDGES 1600000
#define IN_C 128
#define HID_C 256
#define OUT_C 128

// ================= CSR build =================
__global__ void hist_deg(const int* __restrict__ rows, int* __restrict__ deg, int E)
{
    int e = blockIdx.x * blockDim.x + threadIdx.x;
    if (e < E) atomicAdd(&deg[rows[e]], 1);
}

#define SCAN_BLOCK 256
#define SCAN_ELEMS 1024

// per-block exclusive scan of deg -> excl (within-block), block totals -> bsum
__global__ __launch_bounds__(SCAN_BLOCK) void scan1(const int* __restrict__ deg,
                                                    int* __restrict__ excl,
                                                    int* __restrict__ bsum, int N)
{
    __shared__ int sh[SCAN_BLOCK];
    int t = threadIdx.x;
    int base = blockIdx.x * SCAN_ELEMS + t * 4;
    int v[4];
    #pragma unroll
    for (int i = 0; i < 4; ++i) {
        int idx = base + i;
        v[i] = (idx < N) ? deg[idx] : 0;
    }
    int s = v[0] + v[1] + v[2] + v[3];
    sh[t] = s;
    __syncthreads();
    for (int d = 1; d < SCAN_BLOCK; d <<= 1) {
        int add = (t >= d) ? sh[t - d] : 0;
        __syncthreads();
        sh[t] += add;
        __syncthreads();
    }
    int excl_t = sh[t] - s;  // exclusive prefix of this thread's 4-chunk
    int p = excl_t;
    #pragma unroll
    for (int i = 0; i < 4; ++i) {
        int idx = base + i;
        if (idx < N) excl[idx] = p;
        p += v[i];
    }
    if (t == SCAN_BLOCK - 1) bsum[blockIdx.x] = sh[t];
}

// single-block exclusive scan of block sums (NB <= 128)
__global__ void scan2(const int* __restrict__ bsum, int* __restrict__ boff, int NB)
{
    __shared__ int sh[128];
    int t = threadIdx.x;
    int v = (t < NB) ? bsum[t] : 0;
    sh[t] = v;
    __syncthreads();
    for (int d = 1; d < 128; d <<= 1) {
        int add = (t >= d) ? sh[t - d] : 0;
        __syncthreads();
        sh[t] += add;
        __syncthreads();
    }
    if (t < NB) boff[t] = sh[t] - v;
}

// add block offsets in-place; also init cursor
__global__ void scan3(int* __restrict__ row_start, const int* __restrict__ boff,
                      int* __restrict__ cursor, int N)
{
    int i = blockIdx.x * blockDim.x + threadIdx.x;
    if (i < N) {
        int v = row_start[i] + boff[i >> 10];
        row_start[i] = v;
        cursor[i] = v;
    }
}

__global__ void scatter_edges(const int* __restrict__ rows, const int* __restrict__ cols,
                              const float* __restrict__ vals, int* __restrict__ cursor,
                              int* __restrict__ csr_col, float* __restrict__ csr_val, int E)
{
    int e = blockIdx.x * blockDim.x + threadIdx.x;
    if (e < E) {
        int r = rows[e];
        int pos = atomicAdd(&cursor[r], 1);
        csr_col[pos] = cols[e];
        csr_val[pos] = vals[e];
    }
}

// ================= gather SpMM: one wave per row, no atomics =================
template<int C>
__global__ __launch_bounds__(256) void spmm_gather(
    const float* __restrict__ H, const int* __restrict__ row_start,
    const int* __restrict__ deg, const int* __restrict__ csr_col,
    const float* __restrict__ csr_val, float* __restrict__ out, int N)
{
    int wid = threadIdx.x >> 6;
    int lane = threadIdx.x & 63;
    int row = blockIdx.x * (blockDim.x >> 6) + wid;
    if (row >= N) return;
    int start = row_start[row];
    int end = start + deg[row];

    if constexpr (C == 256) {
        const int off = lane * 4;
        float4 acc = {0.f, 0.f, 0.f, 0.f};
        int j = start;
        for (; j + 1 < end; j += 2) {
            int c0 = csr_col[j], c1 = csr_col[j + 1];
            float v0 = csr_val[j], v1 = csr_val[j + 1];
            float4 h0 = *(const float4*)(H + (size_t)c0 * C + off);
            float4 h1 = *(const float4*)(H + (size_t)c1 * C + off);
            acc.x += v0 * h0.x + v1 * h1.x;
            acc.y += v0 * h0.y + v1 * h1.y;
            acc.z += v0 * h0.z + v1 * h1.z;
            acc.w += v0 * h0.w + v1 * h1.w;
        }
        if (j < end) {
            int c0 = csr_col[j];
            float v0 = csr_val[j];
            float4 h0 = *(const float4*)(H + (size_t)c0 * C + off);
            acc.x += v0 * h0.x; acc.y += v0 * h0.y;
            acc.z += v0 * h0.z; acc.w += v0 * h0.w;
        }
        *(float4*)(out + (size_t)row * C + off) = acc;
    } else {
        const int off = lane * 2;
        float2 acc = {0.f, 0.f};
        int j = start;
        for (; j + 1 < end; j += 2) {
            int c0 = csr_col[j], c1 = csr_col[j + 1];
            float v0 = csr_val[j], v1 = csr_val[j + 1];
            float2 h0 = *(const float2*)(H + (size_t)c0 * C + off);
            float2 h1 = *(const float2*)(H + (size_t)c1 * C + off);
            acc.x += v0 * h0.x + v1 * h1.x;
            acc.y += v0 * h0.y + v1 * h1.y;
        }
        if (j < end) {
            int c0 = csr_col[j];
            float v0 = csr_val[j];
            float2 h0 = *(const float2*)(H + (size_t)c0 * C + off);
            acc.x += v0 * h0.x; acc.y += v0 * h0.y;
        }
        *(float2*)(out + (size_t)row * C + off) = acc;
    }
}

// ================= GEMM: Y[n,m] = act(sum_k A[n,k] * W[m,k] + bias[m]) =================
#define BN 64
#define BM 64
#define BK 16

__global__ __launch_bounds__(256) void gemm_bias_act(
    const float* __restrict__ A, const float* __restrict__ W,
    const float* __restrict__ bias, float* __restrict__ Y,
    int N, int K, int M, int relu)
{
    __shared__ float As[BK][BN + 1];
    __shared__ float Ws[BK][BM + 1];

    int bn = blockIdx.x * BN;
    int bm = blockIdx.y * BM;
    int tid = threadIdx.x;
    int tn = tid & 15;
    int tm = tid >> 4;

    float acc[4][4] = {{0.f}};

    int lr = tid >> 2;
    int lk = (tid & 3) * 4;

    for (int k0 = 0; k0 < K; k0 += BK) {
        int n = bn + lr;
        float4 a;
        if (n < N) a = *(const float4*)&A[(size_t)n * K + k0 + lk];
        else       a = float4{0.f, 0.f, 0.f, 0.f};
        As[lk + 0][lr] = a.x; As[lk + 1][lr] = a.y;
        As[lk + 2][lr] = a.z; As[lk + 3][lr] = a.w;

        int m = bm + lr;
        float4 w = *(const float4*)&W[(size_t)m * K + k0 + lk];
        Ws[lk + 0][lr] = w.x; Ws[lk + 1][lr] = w.y;
        Ws[lk + 2][lr] = w.z; Ws[lk + 3][lr] = w.w;

        __syncthreads();

        #pragma unroll
        for (int kk = 0; kk < BK; ++kk) {
            float ar[4], br[4];
            #pragma unroll
            for (int i = 0; i < 4; ++i) ar[i] = As[kk][tn * 4 + i];
            #pragma unroll
            for (int j = 0; j < 4; ++j) br[j] = Ws[kk][tm * 4 + j];
            #pragma unroll
            for (int i = 0; i < 4; ++i)
                #pragma unroll
                for (int j = 0; j < 4; ++j)
                    acc[i][j] += ar[i] * br[j];
        }
        __syncthreads();
    }

    #pragma unroll
    for (int i = 0; i < 4; ++i) {
        int n = bn + tn * 4 + i;
        if (n >= N) continue;
        #pragma unroll
        for (int j = 0; j < 4; ++j) {
            int m = bm + tm * 4 + j;
            float v = acc[i][j] + (bias ? bias[m] : 0.f);
            if (relu) v = fmaxf(v, 0.f);
            Y[(size_t)n * M + m] = v;
        }
    }
}

// ================= L2 normalize rows (C=128), adding bias first =================
__global__ void l2norm_bias(float* __restrict__ Y, const float* __restrict__ bias, int N)
{
    const int C = OUT_C;
    int wid = threadIdx.x >> 6;
    int lane = threadIdx.x & 63;
    int row = blockIdx.x * (blockDim.x >> 6) + wid;
    if (row >= N) return;
    float* p = Y + (size_t)row * C;
    float2 v = *(float2*)&p[lane * 2];
    v.x += bias[lane * 2 + 0];
    v.y += bias[lane * 2 + 1];
    float ss = v.x * v.x + v.y * v.y;
    #pragma unroll
    for (int off = 1; off < 64; off <<= 1)
        ss += __shfl_xor(ss, off);
    float norm = sqrtf(ss);
    float scale = 1.0f / fmaxf(norm, 1e-12f);
    v.x *= scale;
    v.y *= scale;
    *(float2*)&p[lane * 2] = v;
}

extern "C" void kernel_launch(void* const* d_in, const int* in_sizes, int n_in,
                              void* d_out, int out_size, void* d_ws, size_t ws_size,
                              hipStream_t stream) {
    const float* x        = (const float*)d_in[0];
    const int*   edge_row = (const int*)d_in[1];
    const int*   edge_col = (const int*)d_in[2];
    const float* edge_val = (const float*)d_in[3];
    const float* W1       = (const float*)d_in[4];
    const float* b1       = (const float*)d_in[5];
    const float* W2       = (const float*)d_in[6];
    const float* b2       = (const float*)d_in[7];
    const float* W3       = (const float*)d_in[8];
    const float* b3       = (const float*)d_in[9];
    float* out = (float*)d_out;

    const int N = N_NODES, E = N_EDGES;
    const int NB = (N + SCAN_ELEMS - 1) / SCAN_ELEMS;   // 98 <= 128

    // workspace layout
    float* A        = (float*)d_ws;                     // [N,256] (layer1 uses [N,128] view)
    float* B        = A + (size_t)N * HID_C;            // [N,256]
    int*   deg      = (int*)(B + (size_t)N * HID_C);    // [N]
    int*   row_start= deg + N;                          // [N]
    int*   cursor   = row_start + N;                    // [N]
    int*   bsum     = cursor + N;                       // [128]
    int*   boff     = bsum + 128;                       // [128]
    int*   csr_col  = boff + 128;                       // [E]
    float* csr_val  = (float*)(csr_col + E);            // [E]

    // ---- build CSR (graph-safe; d_ws is re-poisoned each call) ----
    hipMemsetAsync(deg, 0, N * sizeof(int), stream);
    hist_deg<<<(E + 255) / 256, 256, 0, stream>>>(edge_row, deg, E);
    scan1<<<NB, SCAN_BLOCK, 0, stream>>>(deg, row_start, bsum, N);
    scan2<<<1, 128, 0, stream>>>(bsum, boff, NB);
    scan3<<<(N + 255) / 256, 256, 0, stream>>>(row_start, boff, cursor, N);
    scatter_edges<<<(E + 255) / 256, 256, 0, stream>>>(edge_row, edge_col, edge_val,
                                                       cursor, csr_col, csr_val, E);

    const int spmm_grid = (N + 3) / 4;  // 4 rows (waves) per 256-thread block

    // Layer 1: A = spmm(x) [N,128]; B = relu(A @ W1.T + b1) [N,256]
    spmm_gather<IN_C><<<spmm_grid, 256, 0, stream>>>(x, row_start, deg, csr_col, csr_val, A, N);
    {
        dim3 grid((N + BN - 1) / BN, HID_C / BM);
        gemm_bias_act<<<grid, 256, 0, stream>>>(A, W1, b1, B, N, IN_C, HID_C, 1);
    }

    // Layer 2: A = spmm(B) [N,256]; B = relu(A @ W2.T + b2) [N,256]
    spmm_gather<HID_C><<<spmm_grid, 256, 0, stream>>>(B, row_start, deg, csr_col, csr_val, A, N);
    {
        dim3 grid((N + BN - 1) / BN, HID_C / BM);
        gemm_bias_act<<<grid, 256, 0, stream>>>(A, W2, b2, B, N, HID_C, HID_C, 1);
    }

    // Layer 3 (W3 first, then spmm): A = B @ W3.T [N,128]; out = spmm(A); normalize(out + b3)
    {
        dim3 grid((N + BN - 1) / BN, OUT_C / BM);
        gemm_bias_act<<<grid, 256, 0, stream>>>(B, W3, nullptr, A, N, HID_C, OUT_C, 0);
    }
    spmm_gather<OUT_C><<<spmm_grid, 256, 0, stream>>>(A, row_start, deg, csr_col, csr_val, out, N);
    l2norm_bias<<<(N + 3) / 4, 256, 0, stream>>>(out, b3, N);
}

// Round 3
// 760.350 us; speedup vs baseline: 4.3215x; 1.7147x over previous
//
#include <hip/hip_runtime.h>
#include <hip/hip_bf16.h>

#define N_NODES 100000
#define N_EDGES 1600000
#define IN_C 128
#define HID_C 256
#define OUT_C 128

typedef __attribute__((ext_vector_type(8))) short bf16x8;
typedef __attribute__((ext_vector_type(4))) float f32x4;

static __device__ __forceinline__ short f2bf(float f) {
    union { float f; unsigned u; } x{f};
    unsigned r = (x.u + 0x7fffu + ((x.u >> 16) & 1u)) >> 16;
    return (short)r;
}
static __device__ __forceinline__ float bf2f(unsigned short u) {
    union { unsigned u; float f; } x{((unsigned)u) << 16};
    return x.f;
}

// ================= CSR build =================
__global__ void hist_deg(const int* __restrict__ rows, int* __restrict__ deg, int E)
{
    int e = blockIdx.x * blockDim.x + threadIdx.x;
    if (e < E) atomicAdd(&deg[rows[e]], 1);
}

#define SCAN_BLOCK 256
#define SCAN_ELEMS 1024

__global__ __launch_bounds__(SCAN_BLOCK) void scan1(const int* __restrict__ deg,
                                                    int* __restrict__ excl,
                                                    int* __restrict__ bsum, int N)
{
    __shared__ int sh[SCAN_BLOCK];
    int t = threadIdx.x;
    int base = blockIdx.x * SCAN_ELEMS + t * 4;
    int v[4];
    #pragma unroll
    for (int i = 0; i < 4; ++i) {
        int idx = base + i;
        v[i] = (idx < N) ? deg[idx] : 0;
    }
    int s = v[0] + v[1] + v[2] + v[3];
    sh[t] = s;
    __syncthreads();
    for (int d = 1; d < SCAN_BLOCK; d <<= 1) {
        int add = (t >= d) ? sh[t - d] : 0;
        __syncthreads();
        sh[t] += add;
        __syncthreads();
    }
    int p = sh[t] - s;
    #pragma unroll
    for (int i = 0; i < 4; ++i) {
        int idx = base + i;
        if (idx < N) excl[idx] = p;
        p += v[i];
    }
    if (t == SCAN_BLOCK - 1) bsum[blockIdx.x] = sh[t];
}

__global__ void scan2(const int* __restrict__ bsum, int* __restrict__ boff, int NB)
{
    __shared__ int sh[128];
    int t = threadIdx.x;
    int v = (t < NB) ? bsum[t] : 0;
    sh[t] = v;
    __syncthreads();
    for (int d = 1; d < 128; d <<= 1) {
        int add = (t >= d) ? sh[t - d] : 0;
        __syncthreads();
        sh[t] += add;
        __syncthreads();
    }
    if (t < NB) boff[t] = sh[t] - v;
}

__global__ void scan3(int* __restrict__ row_start, const int* __restrict__ boff,
                      int* __restrict__ cursor, int N)
{
    int i = blockIdx.x * blockDim.x + threadIdx.x;
    if (i < N) {
        int v = row_start[i] + boff[i >> 10];
        row_start[i] = v;
        cursor[i] = v;
    }
}

__global__ void scatter_edges(const int* __restrict__ rows, const int* __restrict__ cols,
                              const float* __restrict__ vals, int* __restrict__ cursor,
                              int* __restrict__ csr_col, float* __restrict__ csr_val, int E)
{
    int e = blockIdx.x * blockDim.x + threadIdx.x;
    if (e < E) {
        int r = rows[e];
        int pos = atomicAdd(&cursor[r], 1);
        csr_col[pos] = cols[e];
        csr_val[pos] = vals[e];
    }
}

// ================= casts =================
__global__ void cast_f32_to_bf16(const float* __restrict__ in, short* __restrict__ out, int n)
{
    int i = (blockIdx.x * blockDim.x + threadIdx.x) * 4;
    if (i + 3 < n) {
        float4 v = *(const float4*)(in + i);
        short4 o = {f2bf(v.x), f2bf(v.y), f2bf(v.z), f2bf(v.w)};
        *(short4*)(out + i) = o;
    }
}

// ================= gather SpMM (bf16 in), fp32 accumulate =================
template<int C, bool OUT_BF16>
__global__ __launch_bounds__(256) void spmm_gather_bf16(
    const short* __restrict__ H, const int* __restrict__ row_start,
    const int* __restrict__ deg, const int* __restrict__ csr_col,
    const float* __restrict__ csr_val, void* __restrict__ outv, int N)
{
    int wid = threadIdx.x >> 6;
    int lane = threadIdx.x & 63;
    int row = blockIdx.x * 4 + wid;
    if (row >= N) return;
    int start = row_start[row];
    int end = start + deg[row];

    if constexpr (C == 256) {
        const int off = lane * 4;
        float a0 = 0.f, a1 = 0.f, a2 = 0.f, a3 = 0.f;
        int j = start;
        for (; j + 1 < end; j += 2) {
            int c0 = csr_col[j], c1 = csr_col[j + 1];
            float v0 = csr_val[j], v1 = csr_val[j + 1];
            ushort4 h0 = *(const ushort4*)(H + (size_t)c0 * C + off);
            ushort4 h1 = *(const ushort4*)(H + (size_t)c1 * C + off);
            a0 += v0 * bf2f(h0.x) + v1 * bf2f(h1.x);
            a1 += v0 * bf2f(h0.y) + v1 * bf2f(h1.y);
            a2 += v0 * bf2f(h0.z) + v1 * bf2f(h1.z);
            a3 += v0 * bf2f(h0.w) + v1 * bf2f(h1.w);
        }
        if (j < end) {
            int c0 = csr_col[j];
            float v0 = csr_val[j];
            ushort4 h0 = *(const ushort4*)(H + (size_t)c0 * C + off);
            a0 += v0 * bf2f(h0.x); a1 += v0 * bf2f(h0.y);
            a2 += v0 * bf2f(h0.z); a3 += v0 * bf2f(h0.w);
        }
        if constexpr (OUT_BF16) {
            short4 o = {f2bf(a0), f2bf(a1), f2bf(a2), f2bf(a3)};
            *(short4*)((short*)outv + (size_t)row * C + off) = o;
        } else {
            float4 o = {a0, a1, a2, a3};
            *(float4*)((float*)outv + (size_t)row * C + off) = o;
        }
    } else {
        const int off = lane * 2;
        float a0 = 0.f, a1 = 0.f;
        int j = start;
        for (; j + 1 < end; j += 2) {
            int c0 = csr_col[j], c1 = csr_col[j + 1];
            float v0 = csr_val[j], v1 = csr_val[j + 1];
            ushort2 h0 = *(const ushort2*)(H + (size_t)c0 * C + off);
            ushort2 h1 = *(const ushort2*)(H + (size_t)c1 * C + off);
            a0 += v0 * bf2f(h0.x) + v1 * bf2f(h1.x);
            a1 += v0 * bf2f(h0.y) + v1 * bf2f(h1.y);
        }
        if (j < end) {
            int c0 = csr_col[j];
            float v0 = csr_val[j];
            ushort2 h0 = *(const ushort2*)(H + (size_t)c0 * C + off);
            a0 += v0 * bf2f(h0.x); a1 += v0 * bf2f(h0.y);
        }
        if constexpr (OUT_BF16) {
            short2 o = {f2bf(a0), f2bf(a1)};
            *(short2*)((short*)outv + (size_t)row * C + off) = o;
        } else {
            float2 o = {a0, a1};
            *(float2*)((float*)outv + (size_t)row * C + off) = o;
        }
    }
}

// ================= bf16 MFMA GEMM: Y[n,m] = act(A[n,:] . W[m,:] + b[m]) =================
// A: [N,K] bf16 row-major; W: [M,K] bf16 row-major; Y: [N,M] bf16.
// Block tile 128(n) x 64(m), BK=32, 4 waves (2x2), each wave 64x32 via 4x2 MFMA 16x16x32.
template<int K, int M, bool RELU, bool BIAS>
__global__ __launch_bounds__(256) void gemm_bf16(
    const short* __restrict__ A, const short* __restrict__ W,
    const float* __restrict__ bias, short* __restrict__ Y, int N)
{
    constexpr int BK = 32;
    constexpr int PAD = 8;             // 16B pad: keeps ds_*_b128 16B-aligned, 2-way max conflict
    __shared__ short As[128][BK + PAD];
    __shared__ short Ws[64][BK + PAD];

    const int tid = threadIdx.x;
    const int wid = tid >> 6;
    const int lane = tid & 63;
    const int wm = wid & 1;
    const int wn = wid >> 1;
    const int l15 = lane & 15;
    const int quad = lane >> 4;
    const int bn = blockIdx.x * 128;
    const int bm = blockIdx.y * 64;

    f32x4 acc[4][2] = {};

    for (int k0 = 0; k0 < K; k0 += BK) {
        // stage A tile: 128 rows x 32 k -> 512 chunks of 16B, 2 per thread
        #pragma unroll
        for (int c = 0; c < 2; ++c) {
            int chunk = tid + c * 256;
            int row = chunk >> 2;
            int koff = (chunk & 3) * 8;
            int gr = bn + row;
            ulonglong2 v = {0ull, 0ull};
            if (gr < N) v = *(const ulonglong2*)(A + (size_t)gr * K + k0 + koff);
            *(ulonglong2*)&As[row][koff] = v;
        }
        // stage W tile: 64 rows x 32 k -> 256 chunks, 1 per thread
        {
            int row = tid >> 2;
            int koff = (tid & 3) * 8;
            ulonglong2 v = *(const ulonglong2*)(W + (size_t)(bm + row) * K + k0 + koff);
            *(ulonglong2*)&Ws[row][koff] = v;
        }
        __syncthreads();

        bf16x8 aF[4], bF[2];
        #pragma unroll
        for (int mt = 0; mt < 4; ++mt)
            aF[mt] = *(const bf16x8*)&As[wm * 64 + mt * 16 + l15][quad * 8];
        #pragma unroll
        for (int nt = 0; nt < 2; ++nt)
            bF[nt] = *(const bf16x8*)&Ws[wn * 32 + nt * 16 + l15][quad * 8];

        #pragma unroll
        for (int mt = 0; mt < 4; ++mt)
            #pragma unroll
            for (int nt = 0; nt < 2; ++nt)
                acc[mt][nt] = __builtin_amdgcn_mfma_f32_16x16x32_bf16(
                    aF[mt], bF[nt], acc[mt][nt], 0, 0, 0);
        __syncthreads();
    }

    // epilogue: C/D layout col=lane&15 (m/channel dim), row=quad*4+r (n/node dim)
    #pragma unroll
    for (int nt = 0; nt < 2; ++nt) {
        int col = bm + wn * 32 + nt * 16 + l15;
        float bv = BIAS ? bias[col] : 0.f;
        #pragma unroll
        for (int mt = 0; mt < 4; ++mt) {
            int row0 = bn + wm * 64 + mt * 16 + quad * 4;
            #pragma unroll
            for (int r = 0; r < 4; ++r) {
                int row = row0 + r;
                if (row < N) {
                    float v = acc[mt][nt][r] + bv;
                    if (RELU) v = fmaxf(v, 0.f);
                    Y[(size_t)row * M + col] = f2bf(v);
                }
            }
        }
    }
}

// ================= L2 normalize rows (C=128, fp32), adding bias first =================
__global__ void l2norm_bias(float* __restrict__ Y, const float* __restrict__ bias, int N)
{
    const int C = OUT_C;
    int wid = threadIdx.x >> 6;
    int lane = threadIdx.x & 63;
    int row = blockIdx.x * 4 + wid;
    if (row >= N) return;
    float* p = Y + (size_t)row * C;
    float2 v = *(float2*)&p[lane * 2];
    v.x += bias[lane * 2 + 0];
    v.y += bias[lane * 2 + 1];
    float ss = v.x * v.x + v.y * v.y;
    #pragma unroll
    for (int off = 1; off < 64; off <<= 1)
        ss += __shfl_xor(ss, off);
    float scale = 1.0f / fmaxf(sqrtf(ss), 1e-12f);
    v.x *= scale;
    v.y *= scale;
    *(float2*)&p[lane * 2] = v;
}

extern "C" void kernel_launch(void* const* d_in, const int* in_sizes, int n_in,
                              void* d_out, int out_size, void* d_ws, size_t ws_size,
                              hipStream_t stream) {
    const float* x        = (const float*)d_in[0];
    const int*   edge_row = (const int*)d_in[1];
    const int*   edge_col = (const int*)d_in[2];
    const float* edge_val = (const float*)d_in[3];
    const float* W1       = (const float*)d_in[4];
    const float* b1       = (const float*)d_in[5];
    const float* W2       = (const float*)d_in[6];
    const float* b2       = (const float*)d_in[7];
    const float* W3       = (const float*)d_in[8];
    const float* b3       = (const float*)d_in[9];
    float* out = (float*)d_out;

    const int N = N_NODES, E = N_EDGES;
    const int NB = (N + SCAN_ELEMS - 1) / SCAN_ELEMS;   // 98

    // workspace layout
    short* xbf = (short*)d_ws;                    // [N,128] bf16
    short* Hbf = xbf + (size_t)N * IN_C;          // [N,256] bf16 (spmm outputs / gemm3 out)
    short* Gbf = Hbf + (size_t)N * HID_C;         // [N,256] bf16 (gemm outputs)
    short* W1b = Gbf + (size_t)N * HID_C;         // [256,128]
    short* W2b = W1b + HID_C * IN_C;              // [256,256]
    short* W3b = W2b + HID_C * HID_C;             // [128,256]
    int* deg = (int*)(((uintptr_t)(W3b + OUT_C * HID_C) + 15) & ~(uintptr_t)15);
    int* row_start = deg + N;
    int* cursor    = row_start + N;
    int* bsum      = cursor + N;
    int* boff      = bsum + 128;
    int* csr_col   = boff + 128;
    float* csr_val = (float*)(csr_col + E);

    // ---- build CSR ----
    hipMemsetAsync(deg, 0, N * sizeof(int), stream);
    hist_deg<<<(E + 255) / 256, 256, 0, stream>>>(edge_row, deg, E);
    scan1<<<NB, SCAN_BLOCK, 0, stream>>>(deg, row_start, bsum, N);
    scan2<<<1, 128, 0, stream>>>(bsum, boff, NB);
    scan3<<<(N + 255) / 256, 256, 0, stream>>>(row_start, boff, cursor, N);
    scatter_edges<<<(E + 255) / 256, 256, 0, stream>>>(edge_row, edge_col, edge_val,
                                                       cursor, csr_col, csr_val, E);

    // ---- casts ----
    cast_f32_to_bf16<<<(N * IN_C / 4 + 255) / 256, 256, 0, stream>>>(x, xbf, N * IN_C);
    cast_f32_to_bf16<<<(HID_C * IN_C / 4 + 255) / 256, 256, 0, stream>>>(W1, W1b, HID_C * IN_C);
    cast_f32_to_bf16<<<(HID_C * HID_C / 4 + 255) / 256, 256, 0, stream>>>(W2, W2b, HID_C * HID_C);
    cast_f32_to_bf16<<<(OUT_C * HID_C / 4 + 255) / 256, 256, 0, stream>>>(W3, W3b, OUT_C * HID_C);

    const int spmm_grid = (N + 3) / 4;
    const int gemm_gx = (N + 127) / 128;

    // Layer 1: S1 = spmm(xbf) [N,128] -> Hbf; G1 = relu(S1@W1.T+b1) [N,256] -> Gbf
    spmm_gather_bf16<IN_C, true><<<spmm_grid, 256, 0, stream>>>(
        xbf, row_start, deg, csr_col, csr_val, Hbf, N);
    gemm_bf16<IN_C, HID_C, true, true><<<dim3(gemm_gx, HID_C / 64), 256, 0, stream>>>(
        Hbf, W1b, b1, Gbf, N);

    // Layer 2: S2 = spmm(G1) [N,256] -> Hbf; G2 = relu(S2@W2.T+b2) [N,256] -> Gbf
    spmm_gather_bf16<HID_C, true><<<spmm_grid, 256, 0, stream>>>(
        Gbf, row_start, deg, csr_col, csr_val, Hbf, N);
    gemm_bf16<HID_C, HID_C, true, true><<<dim3(gemm_gx, HID_C / 64), 256, 0, stream>>>(
        Hbf, W2b, b2, Gbf, N);

    // Layer 3 (W3 first): G3 = G2@W3.T [N,128] -> Hbf; out = spmm(G3) fp32; normalize(out+b3)
    gemm_bf16<HID_C, OUT_C, false, false><<<dim3(gemm_gx, OUT_C / 64), 256, 0, stream>>>(
        Gbf, W3b, nullptr, Hbf, N);
    spmm_gather_bf16<OUT_C, false><<<spmm_grid, 256, 0, stream>>>(
        Hbf, row_start, deg, csr_col, csr_val, out, N);
    l2norm_bias<<<spmm_grid, 256, 0, stream>>>(out, b3, N);
}

// Round 4
// 671.292 us; speedup vs baseline: 4.8948x; 1.1327x over previous
//
#include <hip/hip_runtime.h>
#include <hip/hip_bf16.h>

#define N_NODES 100000
#define N_EDGES 1600000
#define IN_C 128
#define HID_C 256
#define OUT_C 128

typedef __attribute__((ext_vector_type(8))) short bf16x8;
typedef __attribute__((ext_vector_type(4))) float f32x4;

static __device__ __forceinline__ short f2bf(float f) {
    union { float f; unsigned u; } x{f};
    unsigned r = (x.u + 0x7fffu + ((x.u >> 16) & 1u)) >> 16;
    return (short)r;
}
static __device__ __forceinline__ float bf2f(unsigned short u) {
    union { unsigned u; float f; } x{((unsigned)u) << 16};
    return x.f;
}

// ================= CSR build =================
__global__ void hist_deg(const int* __restrict__ rows, int* __restrict__ deg, int E)
{
    int e = blockIdx.x * blockDim.x + threadIdx.x;
    if (e < E) atomicAdd(&deg[rows[e]], 1);
}

#define SCAN_BLOCK 256
#define SCAN_ELEMS 1024

__global__ __launch_bounds__(SCAN_BLOCK) void scan1(const int* __restrict__ deg,
                                                    int* __restrict__ excl,
                                                    int* __restrict__ bsum, int N)
{
    __shared__ int sh[SCAN_BLOCK];
    int t = threadIdx.x;
    int base = blockIdx.x * SCAN_ELEMS + t * 4;
    int v[4];
    #pragma unroll
    for (int i = 0; i < 4; ++i) {
        int idx = base + i;
        v[i] = (idx < N) ? deg[idx] : 0;
    }
    int s = v[0] + v[1] + v[2] + v[3];
    sh[t] = s;
    __syncthreads();
    for (int d = 1; d < SCAN_BLOCK; d <<= 1) {
        int add = (t >= d) ? sh[t - d] : 0;
        __syncthreads();
        sh[t] += add;
        __syncthreads();
    }
    int p = sh[t] - s;
    #pragma unroll
    for (int i = 0; i < 4; ++i) {
        int idx = base + i;
        if (idx < N) excl[idx] = p;
        p += v[i];
    }
    if (t == SCAN_BLOCK - 1) bsum[blockIdx.x] = sh[t];
}

__global__ void scan2(const int* __restrict__ bsum, int* __restrict__ boff, int NB)
{
    __shared__ int sh[128];
    int t = threadIdx.x;
    int v = (t < NB) ? bsum[t] : 0;
    sh[t] = v;
    __syncthreads();
    for (int d = 1; d < 128; d <<= 1) {
        int add = (t >= d) ? sh[t - d] : 0;
        __syncthreads();
        sh[t] += add;
        __syncthreads();
    }
    if (t < NB) boff[t] = sh[t] - v;
}

// add block offsets; init cursor; row_start has N+1 entries (row_start[N]=E)
__global__ void scan3(int* __restrict__ row_start, const int* __restrict__ boff,
                      int* __restrict__ cursor, int N, int E)
{
    int i = blockIdx.x * blockDim.x + threadIdx.x;
    if (i < N) {
        int v = row_start[i] + boff[i >> 10];
        row_start[i] = v;
        cursor[i] = v;
    } else if (i == N) {
        row_start[N] = E;
    }
}

// pack (col, val) into int2, scatter into row-sorted order
__global__ void scatter_edges(const int* __restrict__ rows, const int* __restrict__ cols,
                              const float* __restrict__ vals, int* __restrict__ cursor,
                              int2* __restrict__ epk, int E)
{
    int e = blockIdx.x * blockDim.x + threadIdx.x;
    if (e < E) {
        int r = rows[e];
        int pos = atomicAdd(&cursor[r], 1);
        epk[pos] = int2{cols[e], __float_as_int(vals[e])};
    }
}

// ================= fused casts (x, W1, W2, W3 -> bf16) =================
__global__ void cast_all(const float* __restrict__ s0, short* __restrict__ d0, int n0,
                         const float* __restrict__ s1, short* __restrict__ d1, int n1,
                         const float* __restrict__ s2, short* __restrict__ d2, int n2,
                         const float* __restrict__ s3, short* __restrict__ d3, int n3)
{
    int i = (blockIdx.x * blockDim.x + threadIdx.x) * 4;
    const float* s; short* d;
    if (i < n0) { s = s0; d = d0; }
    else if ((i -= n0) < n1) { s = s1; d = d1; }
    else if ((i -= n1) < n2) { s = s2; d = d2; }
    else if ((i -= n2) < n3) { s = s3; d = d3; }
    else return;
    float4 v = *(const float4*)(s + i);
    *(short4*)(d + i) = short4{f2bf(v.x), f2bf(v.y), f2bf(v.z), f2bf(v.w)};
}

// ================= gather SpMM, 4-edge unrolled =================
// MODE 0: write bf16. MODE 2: (C==128) add bias, L2-normalize row, write fp32.
template<int C, int MODE>
__global__ __launch_bounds__(256) void spmm_gather(
    const short* __restrict__ H, const int* __restrict__ row_start,
    const int2* __restrict__ epk, void* __restrict__ outv,
    const float* __restrict__ bias, int N)
{
    constexpr int PL = C / 64;  // channels per lane: 2 or 4
    int wid = threadIdx.x >> 6;
    int lane = threadIdx.x & 63;
    int row = blockIdx.x * 4 + wid;
    if (row >= N) return;
    int start = row_start[row];
    int end = row_start[row + 1];
    const int off = lane * PL;

    float acc[PL] = {};
    int j = start;
    for (; j + 3 < end; j += 4) {
        int2 e0 = epk[j], e1 = epk[j + 1], e2 = epk[j + 2], e3 = epk[j + 3];
        if constexpr (PL == 4) {
            ushort4 h0 = *(const ushort4*)(H + (size_t)e0.x * C + off);
            ushort4 h1 = *(const ushort4*)(H + (size_t)e1.x * C + off);
            ushort4 h2 = *(const ushort4*)(H + (size_t)e2.x * C + off);
            ushort4 h3 = *(const ushort4*)(H + (size_t)e3.x * C + off);
            float v0 = __int_as_float(e0.y), v1 = __int_as_float(e1.y);
            float v2 = __int_as_float(e2.y), v3 = __int_as_float(e3.y);
            acc[0] += v0 * bf2f(h0.x) + v1 * bf2f(h1.x) + v2 * bf2f(h2.x) + v3 * bf2f(h3.x);
            acc[1] += v0 * bf2f(h0.y) + v1 * bf2f(h1.y) + v2 * bf2f(h2.y) + v3 * bf2f(h3.y);
            acc[2] += v0 * bf2f(h0.z) + v1 * bf2f(h1.z) + v2 * bf2f(h2.z) + v3 * bf2f(h3.z);
            acc[3] += v0 * bf2f(h0.w) + v1 * bf2f(h1.w) + v2 * bf2f(h2.w) + v3 * bf2f(h3.w);
        } else {
            ushort2 h0 = *(const ushort2*)(H + (size_t)e0.x * C + off);
            ushort2 h1 = *(const ushort2*)(H + (size_t)e1.x * C + off);
            ushort2 h2 = *(const ushort2*)(H + (size_t)e2.x * C + off);
            ushort2 h3 = *(const ushort2*)(H + (size_t)e3.x * C + off);
            float v0 = __int_as_float(e0.y), v1 = __int_as_float(e1.y);
            float v2 = __int_as_float(e2.y), v3 = __int_as_float(e3.y);
            acc[0] += v0 * bf2f(h0.x) + v1 * bf2f(h1.x) + v2 * bf2f(h2.x) + v3 * bf2f(h3.x);
            acc[1] += v0 * bf2f(h0.y) + v1 * bf2f(h1.y) + v2 * bf2f(h2.y) + v3 * bf2f(h3.y);
        }
    }
    for (; j < end; ++j) {
        int2 e = epk[j];
        float v = __int_as_float(e.y);
        if constexpr (PL == 4) {
            ushort4 h = *(const ushort4*)(H + (size_t)e.x * C + off);
            acc[0] += v * bf2f(h.x); acc[1] += v * bf2f(h.y);
            acc[2] += v * bf2f(h.z); acc[3] += v * bf2f(h.w);
        } else {
            ushort2 h = *(const ushort2*)(H + (size_t)e.x * C + off);
            acc[0] += v * bf2f(h.x); acc[1] += v * bf2f(h.y);
        }
    }

    if constexpr (MODE == 0) {
        if constexpr (PL == 4) {
            short4 o = {f2bf(acc[0]), f2bf(acc[1]), f2bf(acc[2]), f2bf(acc[3])};
            *(short4*)((short*)outv + (size_t)row * C + off) = o;
        } else {
            short2 o = {f2bf(acc[0]), f2bf(acc[1])};
            *(short2*)((short*)outv + (size_t)row * C + off) = o;
        }
    } else {
        // C==128: fused bias + L2 normalize, fp32 out
        float o0 = acc[0] + bias[off + 0];
        float o1 = acc[1] + bias[off + 1];
        float ss = o0 * o0 + o1 * o1;
        #pragma unroll
        for (int d = 1; d < 64; d <<= 1)
            ss += __shfl_xor(ss, d);
        float s = 1.0f / fmaxf(sqrtf(ss), 1e-12f);
        *(float2*)((float*)outv + (size_t)row * C + off) = float2{o0 * s, o1 * s};
    }
}

// ================= bf16 MFMA GEMM (unchanged from R3) =================
template<int K, int M, bool RELU, bool BIAS>
__global__ __launch_bounds__(256) void gemm_bf16(
    const short* __restrict__ A, const short* __restrict__ W,
    const float* __restrict__ bias, short* __restrict__ Y, int N)
{
    constexpr int BK = 32;
    constexpr int PAD = 8;
    __shared__ short As[128][BK + PAD];
    __shared__ short Ws[64][BK + PAD];

    const int tid = threadIdx.x;
    const int wid = tid >> 6;
    const int lane = tid & 63;
    const int wm = wid & 1;
    const int wn = wid >> 1;
    const int l15 = lane & 15;
    const int quad = lane >> 4;
    const int bn = blockIdx.x * 128;
    const int bm = blockIdx.y * 64;

    f32x4 acc[4][2] = {};

    for (int k0 = 0; k0 < K; k0 += BK) {
        #pragma unroll
        for (int c = 0; c < 2; ++c) {
            int chunk = tid + c * 256;
            int row = chunk >> 2;
            int koff = (chunk & 3) * 8;
            int gr = bn + row;
            ulonglong2 v = {0ull, 0ull};
            if (gr < N) v = *(const ulonglong2*)(A + (size_t)gr * K + k0 + koff);
            *(ulonglong2*)&As[row][koff] = v;
        }
        {
            int row = tid >> 2;
            int koff = (tid & 3) * 8;
            ulonglong2 v = *(const ulonglong2*)(W + (size_t)(bm + row) * K + k0 + koff);
            *(ulonglong2*)&Ws[row][koff] = v;
        }
        __syncthreads();

        bf16x8 aF[4], bF[2];
        #pragma unroll
        for (int mt = 0; mt < 4; ++mt)
            aF[mt] = *(const bf16x8*)&As[wm * 64 + mt * 16 + l15][quad * 8];
        #pragma unroll
        for (int nt = 0; nt < 2; ++nt)
            bF[nt] = *(const bf16x8*)&Ws[wn * 32 + nt * 16 + l15][quad * 8];

        #pragma unroll
        for (int mt = 0; mt < 4; ++mt)
            #pragma unroll
            for (int nt = 0; nt < 2; ++nt)
                acc[mt][nt] = __builtin_amdgcn_mfma_f32_16x16x32_bf16(
                    aF[mt], bF[nt], acc[mt][nt], 0, 0, 0);
        __syncthreads();
    }

    #pragma unroll
    for (int nt = 0; nt < 2; ++nt) {
        int col = bm + wn * 32 + nt * 16 + l15;
        float bv = BIAS ? bias[col] : 0.f;
        #pragma unroll
        for (int mt = 0; mt < 4; ++mt) {
            int row0 = bn + wm * 64 + mt * 16 + quad * 4;
            #pragma unroll
            for (int r = 0; r < 4; ++r) {
                int row = row0 + r;
                if (row < N) {
                    float v = acc[mt][nt][r] + bv;
                    if (RELU) v = fmaxf(v, 0.f);
                    Y[(size_t)row * M + col] = f2bf(v);
                }
            }
        }
    }
}

extern "C" void kernel_launch(void* const* d_in, const int* in_sizes, int n_in,
                              void* d_out, int out_size, void* d_ws, size_t ws_size,
                              hipStream_t stream) {
    const float* x        = (const float*)d_in[0];
    const int*   edge_row = (const int*)d_in[1];
    const int*   edge_col = (const int*)d_in[2];
    const float* edge_val = (const float*)d_in[3];
    const float* W1       = (const float*)d_in[4];
    const float* b1       = (const float*)d_in[5];
    const float* W2       = (const float*)d_in[6];
    const float* b2       = (const float*)d_in[7];
    const float* W3       = (const float*)d_in[8];
    const float* b3       = (const float*)d_in[9];
    float* out = (float*)d_out;

    const int N = N_NODES, E = N_EDGES;
    const int NB = (N + SCAN_ELEMS - 1) / SCAN_ELEMS;   // 98

    // workspace layout
    short* xbf = (short*)d_ws;                    // [N,128] bf16
    short* Hbf = xbf + (size_t)N * IN_C;          // [N,256] bf16
    short* Gbf = Hbf + (size_t)N * HID_C;         // [N,256] bf16
    short* W1b = Gbf + (size_t)N * HID_C;         // [256,128]
    short* W2b = W1b + HID_C * IN_C;              // [256,256]
    short* W3b = W2b + HID_C * HID_C;             // [128,256]
    int* deg = (int*)(((uintptr_t)(W3b + OUT_C * HID_C) + 15) & ~(uintptr_t)15);
    int* row_start = deg + N;                     // [N+1]
    int* cursor    = row_start + (N + 1);
    int* bsum      = cursor + N;
    int* boff      = bsum + 128;
    int2* epk      = (int2*)(((uintptr_t)(boff + 128) + 15) & ~(uintptr_t)15);  // [E]

    // ---- build CSR ----
    hipMemsetAsync(deg, 0, N * sizeof(int), stream);
    hist_deg<<<(E + 255) / 256, 256, 0, stream>>>(edge_row, deg, E);
    scan1<<<NB, SCAN_BLOCK, 0, stream>>>(deg, row_start, bsum, N);
    scan2<<<1, 128, 0, stream>>>(bsum, boff, NB);
    scan3<<<(N + 256) / 256, 256, 0, stream>>>(row_start, boff, cursor, N, E);
    scatter_edges<<<(E + 255) / 256, 256, 0, stream>>>(edge_row, edge_col, edge_val,
                                                       cursor, epk, E);

    // ---- casts (fused) ----
    {
        int n0 = N * IN_C, n1 = HID_C * IN_C, n2 = HID_C * HID_C, n3 = OUT_C * HID_C;
        int total4 = (n0 + n1 + n2 + n3) / 4;
        cast_all<<<(total4 + 255) / 256, 256, 0, stream>>>(
            x, xbf, n0, W1, W1b, n1, W2, W2b, n2, W3, W3b, n3);
    }

    const int spmm_grid = (N + 3) / 4;
    const int gemm_gx = (N + 127) / 128;

    // Layer 1: Hbf = spmm(xbf) [N,128]; Gbf = relu(Hbf@W1.T+b1) [N,256]
    spmm_gather<IN_C, 0><<<spmm_grid, 256, 0, stream>>>(
        xbf, row_start, epk, Hbf, nullptr, N);
    gemm_bf16<IN_C, HID_C, true, true><<<dim3(gemm_gx, HID_C / 64), 256, 0, stream>>>(
        Hbf, W1b, b1, Gbf, N);

    // Layer 2: Hbf = spmm(Gbf) [N,256]; Gbf = relu(Hbf@W2.T+b2) [N,256]
    spmm_gather<HID_C, 0><<<spmm_grid, 256, 0, stream>>>(
        Gbf, row_start, epk, Hbf, nullptr, N);
    gemm_bf16<HID_C, HID_C, true, true><<<dim3(gemm_gx, HID_C / 64), 256, 0, stream>>>(
        Hbf, W2b, b2, Gbf, N);

    // Layer 3: Hbf = Gbf@W3.T [N,128]; out = normalize(spmm(Hbf) + b3)  (fused)
    gemm_bf16<HID_C, OUT_C, false, false><<<dim3(gemm_gx, OUT_C / 64), 256, 0, stream>>>(
        Gbf, W3b, nullptr, Hbf, N);
    spmm_gather<OUT_C, 2><<<spmm_grid, 256, 0, stream>>>(
        Hbf, row_start, epk, out, b3, N);
}

// Round 5
// 638.145 us; speedup vs baseline: 5.1490x; 1.0519x over previous
//
#include <hip/hip_runtime.h>
#include <hip/hip_bf16.h>

#define N_NODES 100000
#define N_EDGES 1600000
#define IN_C 128
#define HID_C 256
#define OUT_C 128

typedef __attribute__((ext_vector_type(8))) short bf16x8;
typedef __attribute__((ext_vector_type(4))) float f32x4;
typedef __attribute__((ext_vector_type(2))) float f32x2;

static __device__ __forceinline__ short f2bf(float f) {
    union { float f; unsigned u; } x{f};
    unsigned r = (x.u + 0x7fffu + ((x.u >> 16) & 1u)) >> 16;
    return (short)r;
}
// unpack 2 bf16 (packed in one dword) -> f32 pair: lo = d<<16, hi = d & 0xffff0000
static __device__ __forceinline__ f32x2 bfpair(unsigned d) {
    union { unsigned u; float f; } lo, hi;
    lo.u = d << 16;
    hi.u = d & 0xffff0000u;
    return f32x2{lo.f, hi.f};
}

// ================= CSR build =================
__global__ void hist_deg(const int* __restrict__ rows, int* __restrict__ deg, int E)
{
    int e = blockIdx.x * blockDim.x + threadIdx.x;
    if (e < E) atomicAdd(&deg[rows[e]], 1);
}

#define SCAN_BLOCK 256
#define SCAN_ELEMS 1024

__global__ __launch_bounds__(SCAN_BLOCK) void scan1(const int* __restrict__ deg,
                                                    int* __restrict__ excl,
                                                    int* __restrict__ bsum, int N)
{
    __shared__ int sh[SCAN_BLOCK];
    int t = threadIdx.x;
    int base = blockIdx.x * SCAN_ELEMS + t * 4;
    int v[4];
    #pragma unroll
    for (int i = 0; i < 4; ++i) {
        int idx = base + i;
        v[i] = (idx < N) ? deg[idx] : 0;
    }
    int s = v[0] + v[1] + v[2] + v[3];
    sh[t] = s;
    __syncthreads();
    for (int d = 1; d < SCAN_BLOCK; d <<= 1) {
        int add = (t >= d) ? sh[t - d] : 0;
        __syncthreads();
        sh[t] += add;
        __syncthreads();
    }
    int p = sh[t] - s;
    #pragma unroll
    for (int i = 0; i < 4; ++i) {
        int idx = base + i;
        if (idx < N) excl[idx] = p;
        p += v[i];
    }
    if (t == SCAN_BLOCK - 1) bsum[blockIdx.x] = sh[t];
}

__global__ void scan2(const int* __restrict__ bsum, int* __restrict__ boff, int NB)
{
    __shared__ int sh[128];
    int t = threadIdx.x;
    int v = (t < NB) ? bsum[t] : 0;
    sh[t] = v;
    __syncthreads();
    for (int d = 1; d < 128; d <<= 1) {
        int add = (t >= d) ? sh[t - d] : 0;
        __syncthreads();
        sh[t] += add;
        __syncthreads();
    }
    if (t < NB) boff[t] = sh[t] - v;
}

__global__ void scan3(int* __restrict__ row_start, const int* __restrict__ boff,
                      int* __restrict__ cursor, int N, int E)
{
    int i = blockIdx.x * blockDim.x + threadIdx.x;
    if (i < N) {
        int v = row_start[i] + boff[i >> 10];
        row_start[i] = v;
        cursor[i] = v;
    } else if (i == N) {
        row_start[N] = E;
    }
}

__global__ void scatter_edges(const int* __restrict__ rows, const int* __restrict__ cols,
                              const float* __restrict__ vals, int* __restrict__ cursor,
                              int2* __restrict__ epk, int E)
{
    int e = blockIdx.x * blockDim.x + threadIdx.x;
    if (e < E) {
        int r = rows[e];
        int pos = atomicAdd(&cursor[r], 1);
        epk[pos] = int2{cols[e], __float_as_int(vals[e])};
    }
}

// ================= fused casts (x, W1, W2, W3 -> bf16) =================
__global__ void cast_all(const float* __restrict__ s0, short* __restrict__ d0, int n0,
                         const float* __restrict__ s1, short* __restrict__ d1, int n1,
                         const float* __restrict__ s2, short* __restrict__ d2, int n2,
                         const float* __restrict__ s3, short* __restrict__ d3, int n3)
{
    int i = (blockIdx.x * blockDim.x + threadIdx.x) * 4;
    const float* s; short* d;
    if (i < n0) { s = s0; d = d0; }
    else if ((i -= n0) < n1) { s = s1; d = d1; }
    else if ((i -= n1) < n2) { s = s2; d = d2; }
    else if ((i -= n2) < n3) { s = s3; d = d3; }
    else return;
    float4 v = *(const float4*)(s + i);
    *(short4*)(d + i) = short4{f2bf(v.x), f2bf(v.y), f2bf(v.z), f2bf(v.w)};
}

// ================= gather SpMM, batched (8 edges in flight) =================
// ND = dwords gathered per lane (1 for C=128, 2 for C=256)
template<int B, int ND>
static __device__ __forceinline__ void spmm_batch(
    const unsigned* __restrict__ Hb, const int2* __restrict__ epk,
    int j, int loff, f32x2* acc)
{
    int2 e[B];
    #pragma unroll
    for (int b = 0; b < B; ++b) e[b] = epk[j + b];
    uint2 g[B];
    #pragma unroll
    for (int b = 0; b < B; ++b) {
        const unsigned* p = Hb + (size_t)e[b].x * (64 * ND) + loff;
        if constexpr (ND == 2) g[b] = *(const uint2*)p;
        else                   g[b].x = *p;
    }
    #pragma unroll
    for (int b = 0; b < B; ++b) {
        float v = __int_as_float(e[b].y);
        acc[0] += v * bfpair(g[b].x);
        if constexpr (ND == 2) acc[1] += v * bfpair(g[b].y);
    }
}

// MODE 0: write bf16. MODE 2: (C==128) add bias, L2-normalize row, write fp32.
template<int C, int MODE>
__global__ __launch_bounds__(256) void spmm_gather(
    const short* __restrict__ H, const int* __restrict__ row_start,
    const int2* __restrict__ epk, void* __restrict__ outv,
    const float* __restrict__ bias, int N)
{
    constexpr int PL = C / 64;   // channels per lane
    constexpr int ND = PL / 2;   // dwords per lane
    int wid = threadIdx.x >> 6;
    int lane = threadIdx.x & 63;
    int row = blockIdx.x * 4 + wid;
    if (row >= N) return;
    int j = row_start[row];
    int end = row_start[row + 1];
    const unsigned* Hb = (const unsigned*)H;
    const int loff = lane * ND;

    f32x2 acc[ND];
    #pragma unroll
    for (int d = 0; d < ND; ++d) acc[d] = f32x2{0.f, 0.f};

    for (; j + 8 <= end; j += 8) spmm_batch<8, ND>(Hb, epk, j, loff, acc);
    if (j + 4 <= end) { spmm_batch<4, ND>(Hb, epk, j, loff, acc); j += 4; }
    if (j + 2 <= end) { spmm_batch<2, ND>(Hb, epk, j, loff, acc); j += 2; }
    if (j < end)      { spmm_batch<1, ND>(Hb, epk, j, loff, acc); }

    if constexpr (MODE == 0) {
        unsigned od[ND];
        #pragma unroll
        for (int d = 0; d < ND; ++d)
            od[d] = (unsigned)(unsigned short)f2bf(acc[d].x)
                  | ((unsigned)(unsigned short)f2bf(acc[d].y) << 16);
        unsigned* orow = (unsigned*)outv + (size_t)row * (64 * ND) + loff;
        if constexpr (ND == 2) *(uint2*)orow = uint2{od[0], od[1]};
        else                   *orow = od[0];
    } else {
        // C==128 (ND==1): fused bias + L2 normalize, fp32 out
        int ch = lane * 2;
        float o0 = acc[0].x + bias[ch];
        float o1 = acc[0].y + bias[ch + 1];
        float ss = o0 * o0 + o1 * o1;
        #pragma unroll
        for (int d = 1; d < 64; d <<= 1)
            ss += __shfl_xor(ss, d);
        float s = 1.0f / fmaxf(sqrtf(ss), 1e-12f);
        *(float2*)((float*)outv + (size_t)row * C + ch) = float2{o0 * s, o1 * s};
    }
}

// ================= bf16 MFMA GEMM (unchanged) =================
template<int K, int M, bool RELU, bool BIAS>
__global__ __launch_bounds__(256) void gemm_bf16(
    const short* __restrict__ A, const short* __restrict__ W,
    const float* __restrict__ bias, short* __restrict__ Y, int N)
{
    constexpr int BK = 32;
    constexpr int PAD = 8;
    __shared__ short As[128][BK + PAD];
    __shared__ short Ws[64][BK + PAD];

    const int tid = threadIdx.x;
    const int wid = tid >> 6;
    const int lane = tid & 63;
    const int wm = wid & 1;
    const int wn = wid >> 1;
    const int l15 = lane & 15;
    const int quad = lane >> 4;
    const int bn = blockIdx.x * 128;
    const int bm = blockIdx.y * 64;

    f32x4 acc[4][2] = {};

    for (int k0 = 0; k0 < K; k0 += BK) {
        #pragma unroll
        for (int c = 0; c < 2; ++c) {
            int chunk = tid + c * 256;
            int row = chunk >> 2;
            int koff = (chunk & 3) * 8;
            int gr = bn + row;
            ulonglong2 v = {0ull, 0ull};
            if (gr < N) v = *(const ulonglong2*)(A + (size_t)gr * K + k0 + koff);
            *(ulonglong2*)&As[row][koff] = v;
        }
        {
            int row = tid >> 2;
            int koff = (tid & 3) * 8;
            ulonglong2 v = *(const ulonglong2*)(W + (size_t)(bm + row) * K + k0 + koff);
            *(ulonglong2*)&Ws[row][koff] = v;
        }
        __syncthreads();

        bf16x8 aF[4], bF[2];
        #pragma unroll
        for (int mt = 0; mt < 4; ++mt)
            aF[mt] = *(const bf16x8*)&As[wm * 64 + mt * 16 + l15][quad * 8];
        #pragma unroll
        for (int nt = 0; nt < 2; ++nt)
            bF[nt] = *(const bf16x8*)&Ws[wn * 32 + nt * 16 + l15][quad * 8];

        #pragma unroll
        for (int mt = 0; mt < 4; ++mt)
            #pragma unroll
            for (int nt = 0; nt < 2; ++nt)
                acc[mt][nt] = __builtin_amdgcn_mfma_f32_16x16x32_bf16(
                    aF[mt], bF[nt], acc[mt][nt], 0, 0, 0);
        __syncthreads();
    }

    #pragma unroll
    for (int nt = 0; nt < 2; ++nt) {
        int col = bm + wn * 32 + nt * 16 + l15;
        float bv = BIAS ? bias[col] : 0.f;
        #pragma unroll
        for (int mt = 0; mt < 4; ++mt) {
            int row0 = bn + wm * 64 + mt * 16 + quad * 4;
            #pragma unroll
            for (int r = 0; r < 4; ++r) {
                int row = row0 + r;
                if (row < N) {
                    float v = acc[mt][nt][r] + bv;
                    if (RELU) v = fmaxf(v, 0.f);
                    Y[(size_t)row * M + col] = f2bf(v);
                }
            }
        }
    }
}

extern "C" void kernel_launch(void* const* d_in, const int* in_sizes, int n_in,
                              void* d_out, int out_size, void* d_ws, size_t ws_size,
                              hipStream_t stream) {
    const float* x        = (const float*)d_in[0];
    const int*   edge_row = (const int*)d_in[1];
    const int*   edge_col = (const int*)d_in[2];
    const float* edge_val = (const float*)d_in[3];
    const float* W1       = (const float*)d_in[4];
    const float* b1       = (const float*)d_in[5];
    const float* W2       = (const float*)d_in[6];
    const float* b2       = (const float*)d_in[7];
    const float* W3       = (const float*)d_in[8];
    const float* b3       = (const float*)d_in[9];
    float* out = (float*)d_out;

    const int N = N_NODES, E = N_EDGES;
    const int NB = (N + SCAN_ELEMS - 1) / SCAN_ELEMS;   // 98

    // workspace layout
    short* xbf = (short*)d_ws;                    // [N,128] bf16
    short* Hbf = xbf + (size_t)N * IN_C;          // [N,256] bf16
    short* Gbf = Hbf + (size_t)N * HID_C;         // [N,256] bf16
    short* W1b = Gbf + (size_t)N * HID_C;         // [256,128]
    short* W2b = W1b + HID_C * IN_C;              // [256,256]
    short* W3b = W2b + HID_C * HID_C;             // [128,256]
    int* deg = (int*)(((uintptr_t)(W3b + OUT_C * HID_C) + 15) & ~(uintptr_t)15);
    int* row_start = deg + N;                     // [N+1]
    int* cursor    = row_start + (N + 1);
    int* bsum      = cursor + N;
    int* boff      = bsum + 128;
    int2* epk      = (int2*)(((uintptr_t)(boff + 128) + 15) & ~(uintptr_t)15);  // [E]

    // ---- build CSR ----
    hipMemsetAsync(deg, 0, N * sizeof(int), stream);
    hist_deg<<<(E + 255) / 256, 256, 0, stream>>>(edge_row, deg, E);
    scan1<<<NB, SCAN_BLOCK, 0, stream>>>(deg, row_start, bsum, N);
    scan2<<<1, 128, 0, stream>>>(bsum, boff, NB);
    scan3<<<(N + 256) / 256, 256, 0, stream>>>(row_start, boff, cursor, N, E);
    scatter_edges<<<(E + 255) / 256, 256, 0, stream>>>(edge_row, edge_col, edge_val,
                                                       cursor, epk, E);

    // ---- casts (fused) ----
    {
        int n0 = N * IN_C, n1 = HID_C * IN_C, n2 = HID_C * HID_C, n3 = OUT_C * HID_C;
        int total4 = (n0 + n1 + n2 + n3) / 4;
        cast_all<<<(total4 + 255) / 256, 256, 0, stream>>>(
            x, xbf, n0, W1, W1b, n1, W2, W2b, n2, W3, W3b, n3);
    }

    const int spmm_grid = (N + 3) / 4;
    const int gemm_gx = (N + 127) / 128;

    // Layer 1: Hbf = spmm(xbf) [N,128]; Gbf = relu(Hbf@W1.T+b1) [N,256]
    spmm_gather<IN_C, 0><<<spmm_grid, 256, 0, stream>>>(
        xbf, row_start, epk, Hbf, nullptr, N);
    gemm_bf16<IN_C, HID_C, true, true><<<dim3(gemm_gx, HID_C / 64), 256, 0, stream>>>(
        Hbf, W1b, b1, Gbf, N);

    // Layer 2: Hbf = spmm(Gbf) [N,256]; Gbf = relu(Hbf@W2.T+b2) [N,256]
    spmm_gather<HID_C, 0><<<spmm_grid, 256, 0, stream>>>(
        Gbf, row_start, epk, Hbf, nullptr, N);
    gemm_bf16<HID_C, HID_C, true, true><<<dim3(gemm_gx, HID_C / 64), 256, 0, stream>>>(
        Hbf, W2b, b2, Gbf, N);

    // Layer 3: Hbf = Gbf@W3.T [N,128]; out = normalize(spmm(Hbf) + b3)  (fused)
    gemm_bf16<HID_C, OUT_C, false, false><<<dim3(gemm_gx, OUT_C / 64), 256, 0, stream>>>(
        Gbf, W3b, nullptr, Hbf, N);
    spmm_gather<OUT_C, 2><<<spmm_grid, 256, 0, stream>>>(
        Hbf, row_start, epk, out, b3, N);
}